// Round 2
// baseline (362.060 us; speedup 1.0000x reference)
//
#include <hip/hip_runtime.h>

typedef __bf16 bf16_t;
typedef __bf16 bf16x8 __attribute__((ext_vector_type(8)));
typedef float f32x4 __attribute__((ext_vector_type(4)));

#define MFMA16(a, b, c) __builtin_amdgcn_mfma_f32_16x16x32_bf16(a, b, c, 0, 0, 0)

#define F_W 128
#define ED 512
#define NH 8
#define HD 64
#define B_NW 512

typedef const __attribute__((address_space(1))) void gvoid_t;
typedef __attribute__((address_space(3))) void lvoid_t;
__device__ __forceinline__ void gload16(const void* g, void* l) {
    __builtin_amdgcn_global_load_lds((gvoid_t*)g, (lvoid_t*)l, 16, 0, 0);
}

// ---------------- prep: transpose + convert weights to bf16 ----------------
__global__ __launch_bounds__(256) void prep_kernel(
    const float* __restrict__ qkv_w,   // [512][1536]
    const float* __restrict__ proj_w,  // [512][512]
    bf16_t* __restrict__ qkv_wt,       // [1536][512]
    bf16_t* __restrict__ proj_wt) {    // [512][512]
    int idx = blockIdx.x * 256 + threadIdx.x;
    if (idx < 1536 * 512) {
        int n = idx >> 9, k = idx & 511;
        qkv_wt[idx] = (bf16_t)qkv_w[k * 1536 + n];
    }
    if (idx < 512 * 512) {
        int n = idx >> 9, k = idx & 511;
        proj_wt[idx] = (bf16_t)proj_w[k * 512 + n];
    }
}

// ---------------- fused QKV projection + windowed attention ----------------
// One block per (window, head). 256 threads = 4 waves. LDS plan (48 KB):
//   [0,16K):  x_s fp32 [128][32] (Phase A)  -> q_lds bf16 [128][64] swz8
//   [16K,28K): wt_s bf16 [192][32] (Phase A) -> k_lds bf16 [128][64] swz8 ([16K,32K))
//   [0,32K):  p_lds bf16 [128][128] swz16 (aliases q+k after S)
//   [32K,48K): vt_lds bf16 [64][128] swz16 (persists)
__global__ __launch_bounds__(256, 3) void fused_attn_kernel(
    const float* __restrict__ x,        // [B_NW*F_W][ED] fp32
    const float* __restrict__ adj,      // [8][8][128][128] fp32
    const float* __restrict__ qkv_b,    // [1536]
    const bf16_t* __restrict__ qkv_wt,  // [1536][512] bf16 (n-major)
    bf16_t* __restrict__ attn_out) {    // [B_NW*F_W][ED] bf16
    __shared__ __align__(16) char smem[49152];
    float*  x_s32  = (float*)smem;              // [128][32] f32
    bf16_t* wt_s   = (bf16_t*)(smem + 16384);   // [192][32] bf16
    bf16_t* q_lds  = (bf16_t*)smem;             // [128][64]
    bf16_t* k_lds  = (bf16_t*)(smem + 16384);   // [128][64]
    bf16_t* p_lds  = (bf16_t*)smem;             // [128][128]
    bf16_t* vt_lds = (bf16_t*)(smem + 32768);   // [64][128]

    const int tid  = threadIdx.x;
    const int wave = tid >> 6;
    const int lane = tid & 63;
    const int lrow = lane & 15;
    const int lgrp = lane >> 4;
    const int w = blockIdx.x >> 3;
    const int h = blockIdx.x & 7;
    const int bidx = w >> 6;

    const float* xw = x + (size_t)w * F_W * ED;

    // per-lane preswizzled source columns for global_load_lds staging
    // x chunks: 1KB = 8 rows x 32 f32; lane l -> row l>>3, col (l&7)*4, swz (row&7)<<2
    const int xrow_l = lane >> 3;
    const int xcol_l = (((lane & 7) * 4) ^ ((xrow_l & 7) << 2));
    // wt chunks: 1KB = 16 rows x 32 bf16; lane l -> row l>>2, col (l&3)*8, swz (row&3)<<3
    const int wrow_l = lane >> 2;
    const int wcol_l = ((((lane & 3) * 8)) ^ ((wrow_l & 3) << 3));

    // ---------------- Phase A: QKV GEMM (M=128, N=192, K=512) --------------
    f32x4 acc[2][12];
#pragma unroll
    for (int mf = 0; mf < 2; ++mf)
#pragma unroll
        for (int nf = 0; nf < 12; ++nf) acc[mf][nf] = (f32x4)0.0f;

    for (int kc = 0; kc < 16; ++kc) {
        const int k0 = kc * 32;
        __syncthreads();
        // x: 16 chunks of 8 rows; wave does 4
#pragma unroll
        for (int i = 0; i < 4; ++i) {
            int c = wave * 4 + i;
            const float* g = xw + (size_t)(c * 8 + xrow_l) * ED + k0 + xcol_l;
            gload16(g, x_s32 + c * 256);
        }
        // wt: 12 chunks of 16 rows; wave does 3
#pragma unroll
        for (int i = 0; i < 3; ++i) {
            int c = wave * 3 + i;
            int r = c * 16 + wrow_l;
            int n = (r >> 6) * 512 + h * 64 + (r & 63);
            const bf16_t* g = qkv_wt + (size_t)n * 512 + k0 + wcol_l;
            gload16(g, wt_s + c * 512);
        }
        __syncthreads();

        bf16x8 a[2], b[12];
#pragma unroll
        for (int mf = 0; mf < 2; ++mf) {
            int row = wave * 32 + mf * 16 + lrow;
            int sw = (row & 7) << 2;
            const float* px = x_s32 + row * 32;
            f32x4 lo = *(const f32x4*)(px + ((lgrp * 8) ^ sw));
            f32x4 hi = *(const f32x4*)(px + ((lgrp * 8 + 4) ^ sw));
            a[mf] = bf16x8{(bf16_t)lo[0], (bf16_t)lo[1], (bf16_t)lo[2], (bf16_t)lo[3],
                           (bf16_t)hi[0], (bf16_t)hi[1], (bf16_t)hi[2], (bf16_t)hi[3]};
        }
#pragma unroll
        for (int nf = 0; nf < 12; ++nf) {
            int row = nf * 16 + lrow;
            b[nf] = *(const bf16x8*)(wt_s + row * 32 + ((lgrp * 8) ^ ((row & 3) << 3)));
        }
#pragma unroll
        for (int mf = 0; mf < 2; ++mf)
#pragma unroll
            for (int nf = 0; nf < 12; ++nf)
                acc[mf][nf] = MFMA16(a[mf], b[nf], acc[mf][nf]);
    }
    __syncthreads();  // Phase A reads done; staging region reusable

    // ------------- write Q (scaled), K, V^T to LDS with bias ---------------
#pragma unroll
    for (int mf = 0; mf < 2; ++mf) {
#pragma unroll
        for (int nf = 0; nf < 12; ++nf) {
            int s = nf >> 2;
            int dl = (nf & 3) * 16 + lrow;
            float bias = qkv_b[s * 512 + h * 64 + dl];
#pragma unroll
            for (int j = 0; j < 4; ++j) {
                int row = wave * 32 + mf * 16 + lgrp * 4 + j;
                float val = acc[mf][nf][j] + bias;
                if (s == 0)      q_lds[row * 64 + (dl ^ ((row & 7) << 3))] = (bf16_t)(val * 0.125f);
                else if (s == 1) k_lds[row * 64 + (dl ^ ((row & 7) << 3))] = (bf16_t)val;
                else             vt_lds[dl * 128 + (row ^ ((dl & 15) << 3))] = (bf16_t)val;
            }
        }
    }
    __syncthreads();

    // ---------------- Phase B: S = Q @ K^T + mask, softmax ------------------
    f32x4 sacc[2][8];
#pragma unroll
    for (int mf = 0; mf < 2; ++mf)
#pragma unroll
        for (int nf = 0; nf < 8; ++nf) sacc[mf][nf] = (f32x4)0.0f;

#pragma unroll
    for (int kb = 0; kb < 2; ++kb) {
        bf16x8 a[2], b[8];
#pragma unroll
        for (int mf = 0; mf < 2; ++mf) {
            int row = wave * 32 + mf * 16 + lrow;
            a[mf] = *(const bf16x8*)(q_lds + row * 64 + ((kb * 32 + lgrp * 8) ^ ((row & 7) << 3)));
        }
#pragma unroll
        for (int nf = 0; nf < 8; ++nf) {
            int row = nf * 16 + lrow;
            b[nf] = *(const bf16x8*)(k_lds + row * 64 + ((kb * 32 + lgrp * 8) ^ ((row & 7) << 3)));
        }
#pragma unroll
        for (int mf = 0; mf < 2; ++mf)
#pragma unroll
            for (int nf = 0; nf < 8; ++nf)
                sacc[mf][nf] = MFMA16(a[mf], b[nf], sacc[mf][nf]);
    }

    // mask add + row softmax (registers + shfl only)
    const float* mbase = adj + ((size_t)(bidx * NH + h)) * F_W * F_W;
#pragma unroll
    for (int mf = 0; mf < 2; ++mf) {
#pragma unroll
        for (int j = 0; j < 4; ++j) {
            int row = wave * 32 + mf * 16 + lgrp * 4 + j;
            const float* mrow = mbase + (size_t)row * F_W;
            float mval[8];
#pragma unroll
            for (int nf = 0; nf < 8; ++nf) mval[nf] = mrow[nf * 16 + lrow];
            float mx = -1e30f;
#pragma unroll
            for (int nf = 0; nf < 8; ++nf) {
                sacc[mf][nf][j] += mval[nf];
                mx = fmaxf(mx, sacc[mf][nf][j]);
            }
#pragma unroll
            for (int d = 1; d < 16; d <<= 1) mx = fmaxf(mx, __shfl_xor(mx, d));
            float sum = 0.f;
#pragma unroll
            for (int nf = 0; nf < 8; ++nf) {
                float p = exp2f((sacc[mf][nf][j] - mx) * 1.44269504f);
                sacc[mf][nf][j] = p;
                sum += p;
            }
#pragma unroll
            for (int d = 1; d < 16; d <<= 1) sum += __shfl_xor(sum, d);
            float r = 1.0f / sum;
#pragma unroll
            for (int nf = 0; nf < 8; ++nf) sacc[mf][nf][j] *= r;
        }
    }
    __syncthreads();  // q/k reads done; overwrite with P
#pragma unroll
    for (int mf = 0; mf < 2; ++mf)
#pragma unroll
        for (int nf = 0; nf < 8; ++nf)
#pragma unroll
            for (int j = 0; j < 4; ++j) {
                int row = wave * 32 + mf * 16 + lgrp * 4 + j;
                int col = nf * 16 + lrow;
                p_lds[row * 128 + (col ^ ((row & 15) << 3))] = (bf16_t)sacc[mf][nf][j];
            }
    __syncthreads();

    // ---------------- Phase C: O = P @ V (M=128, N=64, K=128) --------------
    f32x4 oacc[2][4];
#pragma unroll
    for (int mf = 0; mf < 2; ++mf)
#pragma unroll
        for (int nf = 0; nf < 4; ++nf) oacc[mf][nf] = (f32x4)0.0f;

#pragma unroll
    for (int kb = 0; kb < 4; ++kb) {
        bf16x8 a[2], b[4];
#pragma unroll
        for (int mf = 0; mf < 2; ++mf) {
            int row = wave * 32 + mf * 16 + lrow;
            a[mf] = *(const bf16x8*)(p_lds + row * 128 + ((kb * 32 + lgrp * 8) ^ ((row & 15) << 3)));
        }
#pragma unroll
        for (int nf = 0; nf < 4; ++nf) {
            int d = nf * 16 + lrow;
            b[nf] = *(const bf16x8*)(vt_lds + d * 128 + ((kb * 32 + lgrp * 8) ^ ((d & 15) << 3)));
        }
#pragma unroll
        for (int mf = 0; mf < 2; ++mf)
#pragma unroll
            for (int nf = 0; nf < 4; ++nf)
                oacc[mf][nf] = MFMA16(a[mf], b[nf], oacc[mf][nf]);
    }

    bf16_t* obase = attn_out + (size_t)w * F_W * ED + h * HD;
#pragma unroll
    for (int mf = 0; mf < 2; ++mf)
#pragma unroll
        for (int nf = 0; nf < 4; ++nf)
#pragma unroll
            for (int j = 0; j < 4; ++j) {
                int row = wave * 32 + mf * 16 + lgrp * 4 + j;
                obase[(size_t)row * ED + nf * 16 + lrow] = (bf16_t)oacc[mf][nf][j];
            }
}

// ---------------- output projection GEMM: [65536,512]@[512,512]+b ----------
__global__ __launch_bounds__(256) void proj_kernel(
    const bf16_t* __restrict__ a_g,   // attn_out [65536][512] bf16
    const bf16_t* __restrict__ bt_g,  // proj_wt  [512][512] bf16 (n-major)
    const float* __restrict__ bias,   // [512]
    float* __restrict__ out) {        // [65536][512] fp32
    __shared__ __align__(16) bf16_t sm[8192];
    bf16_t* a_s = sm;         // [128][32]
    bf16_t* b_s = sm + 4096;  // [128][32]
    const int tid = threadIdx.x;
    const int wave = tid >> 6, lane = tid & 63;
    const int lrow = lane & 15, lgrp = lane >> 4;
    const int mtile = blockIdx.x >> 2, ntile = blockIdx.x & 3;
    const size_t m0 = (size_t)mtile * 128;
    const int n0 = ntile * 128;
    const int wrow_l = lane >> 2;
    const int wcol_l = ((((lane & 3) * 8)) ^ ((wrow_l & 3) << 3));

    f32x4 acc[2][8];
#pragma unroll
    for (int mf = 0; mf < 2; ++mf)
#pragma unroll
        for (int nf = 0; nf < 8; ++nf) acc[mf][nf] = (f32x4)0.0f;

    for (int kc = 0; kc < 16; ++kc) {
        const int k0 = kc * 32;
        __syncthreads();
#pragma unroll
        for (int i = 0; i < 2; ++i) {
            int c = wave * 2 + i;
            gload16(a_g + (m0 + c * 16 + wrow_l) * 512 + k0 + wcol_l, a_s + c * 512);
            gload16(bt_g + (size_t)(n0 + c * 16 + wrow_l) * 512 + k0 + wcol_l, b_s + c * 512);
        }
        __syncthreads();
        bf16x8 a[2], b[8];
#pragma unroll
        for (int mf = 0; mf < 2; ++mf) {
            int row = wave * 32 + mf * 16 + lrow;
            a[mf] = *(const bf16x8*)(a_s + row * 32 + ((lgrp * 8) ^ ((row & 3) << 3)));
        }
#pragma unroll
        for (int nf = 0; nf < 8; ++nf) {
            int row = nf * 16 + lrow;
            b[nf] = *(const bf16x8*)(b_s + row * 32 + ((lgrp * 8) ^ ((row & 3) << 3)));
        }
#pragma unroll
        for (int mf = 0; mf < 2; ++mf)
#pragma unroll
            for (int nf = 0; nf < 8; ++nf)
                acc[mf][nf] = MFMA16(a[mf], b[nf], acc[mf][nf]);
    }

#pragma unroll
    for (int nf = 0; nf < 8; ++nf) {
        int col = n0 + nf * 16 + lrow;
        float bv = bias[col];
#pragma unroll
        for (int mf = 0; mf < 2; ++mf)
#pragma unroll
            for (int j = 0; j < 4; ++j) {
                size_t row = m0 + wave * 32 + mf * 16 + lgrp * 4 + j;
                out[row * 512 + col] = acc[mf][nf][j] + bv;
            }
    }
}

extern "C" void kernel_launch(void* const* d_in, const int* in_sizes, int n_in,
                              void* d_out, int out_size, void* d_ws, size_t ws_size,
                              hipStream_t stream) {
    const float* x      = (const float*)d_in[0];
    const float* adj    = (const float*)d_in[1];
    const float* qkv_w  = (const float*)d_in[2];
    const float* qkv_b  = (const float*)d_in[3];
    const float* proj_w = (const float*)d_in[4];
    const float* proj_b = (const float*)d_in[5];
    float* out = (float*)d_out;

    bf16_t* attn_out = (bf16_t*)d_ws;
    bf16_t* qkv_wt   = attn_out + (size_t)B_NW * F_W * ED;
    bf16_t* proj_wt  = qkv_wt + 1536 * 512;

    prep_kernel<<<3072, 256, 0, stream>>>(qkv_w, proj_w, qkv_wt, proj_wt);
    fused_attn_kernel<<<B_NW * NH, 256, 0, stream>>>(x, adj, qkv_b, qkv_wt, attn_out);
    proj_kernel<<<(B_NW * F_W / 128) * (ED / 128), 256, 0, stream>>>(attn_out, proj_wt, proj_b, out);
}

// Round 4
// 336.614 us; speedup vs baseline: 1.0756x; 1.0756x over previous
//
#include <hip/hip_runtime.h>

typedef __bf16 bf16_t;
typedef __bf16 bf16x8 __attribute__((ext_vector_type(8)));
typedef float f32x4 __attribute__((ext_vector_type(4)));

#define MFMA16(a, b, c) __builtin_amdgcn_mfma_f32_16x16x32_bf16(a, b, c, 0, 0, 0)

#define F_W 128
#define ED 512
#define NH 8
#define HD 64
#define B_NW 512

typedef const __attribute__((address_space(1))) void gvoid_t;
typedef __attribute__((address_space(3))) void lvoid_t;
__device__ __forceinline__ void gload16(const void* g, void* l) {
    __builtin_amdgcn_global_load_lds((gvoid_t*)g, (lvoid_t*)l, 16, 0, 0);
}

// ---------------- prep: transpose + convert weights to bf16 ----------------
__global__ __launch_bounds__(256) void prep_kernel(
    const float* __restrict__ qkv_w,   // [512][1536]
    const float* __restrict__ proj_w,  // [512][512]
    bf16_t* __restrict__ qkv_wt,       // [1536][512]
    bf16_t* __restrict__ proj_wt) {    // [512][512]
    int idx = blockIdx.x * 256 + threadIdx.x;
    if (idx < 1536 * 512) {
        int n = idx >> 9, k = idx & 511;
        qkv_wt[idx] = (bf16_t)qkv_w[k * 1536 + n];
    }
    if (idx < 512 * 512) {
        int n = idx >> 9, k = idx & 511;
        proj_wt[idx] = (bf16_t)proj_w[k * 512 + n];
    }
}

// ---------------- fused QKV projection + windowed attention ----------------
// One block per (window, head). XCD-aware remap (T1): XCD x = bid&7 owns
// windows [x*64, x*64+64); the 8 heads of one window are consecutive in
// dispatch on the same XCD -> x-window (256KB) and adj slice become
// L2-resident instead of re-fetched by all 8 XCDs.
// 256 threads = 4 waves. LDS plan (48 KB), identical to round-2 (verified):
//   [0,16K):  x_s fp32 [128][32] (Phase A)  -> q_lds bf16 [128][64] swz8
//   [16K,28K): wt_s bf16 [192][32] (Phase A) -> k_lds bf16 [128][64] swz8
//   [0,32K):  p_lds bf16 [128][128] swz16 (aliases q+k after S)
//   [32K,48K): vt_lds bf16 [64][128] swz16 (persists)
__global__ __launch_bounds__(256, 3) void fused_attn_kernel(
    const float* __restrict__ x,        // [B_NW*F_W][ED] fp32
    const float* __restrict__ adj,      // [8][8][128][128] fp32
    const float* __restrict__ qkv_b,    // [1536]
    const bf16_t* __restrict__ qkv_wt,  // [1536][512] bf16 (n-major)
    bf16_t* __restrict__ attn_out) {    // [B_NW*F_W][ED] bf16
    __shared__ __align__(16) char smem[49152];
    float*  x_s32  = (float*)smem;              // [128][32] f32
    bf16_t* wt_s   = (bf16_t*)(smem + 16384);   // [192][32] bf16
    bf16_t* q_lds  = (bf16_t*)smem;             // [128][64]
    bf16_t* k_lds  = (bf16_t*)(smem + 16384);   // [128][64]
    bf16_t* p_lds  = (bf16_t*)smem;             // [128][128]
    bf16_t* vt_lds = (bf16_t*)(smem + 32768);   // [64][128]

    const int tid  = threadIdx.x;
    const int wave = tid >> 6;
    const int lane = tid & 63;
    const int lrow = lane & 15;
    const int lgrp = lane >> 4;
    // XCD-aware decode (bijective over [0,4096))
    const int bid = blockIdx.x;
    const int w = (bid & 7) * 64 + (bid >> 6);
    const int h = (bid >> 3) & 7;
    const int bidx = bid & 7;   // == w >> 6

    const float* xw = x + (size_t)w * F_W * ED;

    // per-lane preswizzled source columns for global_load_lds staging
    // x chunks: 1KB = 8 rows x 32 f32; lane l -> row l>>3, col (l&7)*4, swz (row&7)<<2
    const int xrow_l = lane >> 3;
    const int xcol_l = (((lane & 7) * 4) ^ ((xrow_l & 7) << 2));
    // wt chunks: 1KB = 16 rows x 32 bf16; lane l -> row l>>2, col (l&3)*8, swz (row&3)<<3
    const int wrow_l = lane >> 2;
    const int wcol_l = ((((lane & 3) * 8)) ^ ((wrow_l & 3) << 3));

    // ---------------- Phase A: QKV GEMM (M=128, N=192, K=512) --------------
    f32x4 acc[2][12];
#pragma unroll
    for (int mf = 0; mf < 2; ++mf)
#pragma unroll
        for (int nf = 0; nf < 12; ++nf) acc[mf][nf] = (f32x4)0.0f;

    for (int kc = 0; kc < 16; ++kc) {
        const int k0 = kc * 32;
        __syncthreads();
        // x: 16 chunks of 8 rows; wave does 4
#pragma unroll
        for (int i = 0; i < 4; ++i) {
            int c = wave * 4 + i;
            const float* g = xw + (size_t)(c * 8 + xrow_l) * ED + k0 + xcol_l;
            gload16(g, x_s32 + c * 256);
        }
        // wt: 12 chunks of 16 rows; wave does 3
#pragma unroll
        for (int i = 0; i < 3; ++i) {
            int c = wave * 3 + i;
            int r = c * 16 + wrow_l;
            int n = (r >> 6) * 512 + h * 64 + (r & 63);
            const bf16_t* g = qkv_wt + (size_t)n * 512 + k0 + wcol_l;
            gload16(g, wt_s + c * 512);
        }
        __syncthreads();

        bf16x8 a[2], b[12];
#pragma unroll
        for (int mf = 0; mf < 2; ++mf) {
            int row = wave * 32 + mf * 16 + lrow;
            int sw = (row & 7) << 2;
            const float* px = x_s32 + row * 32;
            f32x4 lo = *(const f32x4*)(px + ((lgrp * 8) ^ sw));
            f32x4 hi = *(const f32x4*)(px + ((lgrp * 8 + 4) ^ sw));
            a[mf] = bf16x8{(bf16_t)lo[0], (bf16_t)lo[1], (bf16_t)lo[2], (bf16_t)lo[3],
                           (bf16_t)hi[0], (bf16_t)hi[1], (bf16_t)hi[2], (bf16_t)hi[3]};
        }
#pragma unroll
        for (int nf = 0; nf < 12; ++nf) {
            int row = nf * 16 + lrow;
            b[nf] = *(const bf16x8*)(wt_s + row * 32 + ((lgrp * 8) ^ ((row & 3) << 3)));
        }
#pragma unroll
        for (int mf = 0; mf < 2; ++mf)
#pragma unroll
            for (int nf = 0; nf < 12; ++nf)
                acc[mf][nf] = MFMA16(a[mf], b[nf], acc[mf][nf]);
    }
    __syncthreads();  // Phase A reads done; staging region reusable

    // ------------- write Q (scaled), K, V^T to LDS with bias ---------------
#pragma unroll
    for (int mf = 0; mf < 2; ++mf) {
#pragma unroll
        for (int nf = 0; nf < 12; ++nf) {
            int s = nf >> 2;
            int dl = (nf & 3) * 16 + lrow;
            float bias = qkv_b[s * 512 + h * 64 + dl];
#pragma unroll
            for (int j = 0; j < 4; ++j) {
                int row = wave * 32 + mf * 16 + lgrp * 4 + j;
                float val = acc[mf][nf][j] + bias;
                if (s == 0)      q_lds[row * 64 + (dl ^ ((row & 7) << 3))] = (bf16_t)(val * 0.125f);
                else if (s == 1) k_lds[row * 64 + (dl ^ ((row & 7) << 3))] = (bf16_t)val;
                else             vt_lds[dl * 128 + (row ^ ((dl & 15) << 3))] = (bf16_t)val;
            }
        }
    }
    __syncthreads();

    // ---------------- Phase B: S = Q @ K^T + mask, softmax ------------------
    f32x4 sacc[2][8];
#pragma unroll
    for (int mf = 0; mf < 2; ++mf)
#pragma unroll
        for (int nf = 0; nf < 8; ++nf) sacc[mf][nf] = (f32x4)0.0f;

#pragma unroll
    for (int kb = 0; kb < 2; ++kb) {
        bf16x8 a[2], b[8];
#pragma unroll
        for (int mf = 0; mf < 2; ++mf) {
            int row = wave * 32 + mf * 16 + lrow;
            a[mf] = *(const bf16x8*)(q_lds + row * 64 + ((kb * 32 + lgrp * 8) ^ ((row & 7) << 3)));
        }
#pragma unroll
        for (int nf = 0; nf < 8; ++nf) {
            int row = nf * 16 + lrow;
            b[nf] = *(const bf16x8*)(k_lds + row * 64 + ((kb * 32 + lgrp * 8) ^ ((row & 7) << 3)));
        }
#pragma unroll
        for (int mf = 0; mf < 2; ++mf)
#pragma unroll
            for (int nf = 0; nf < 8; ++nf)
                sacc[mf][nf] = MFMA16(a[mf], b[nf], sacc[mf][nf]);
    }

    // mask add + row softmax (registers + shfl only)
    const float* mbase = adj + ((size_t)(bidx * NH + h)) * F_W * F_W;
#pragma unroll
    for (int mf = 0; mf < 2; ++mf) {
#pragma unroll
        for (int j = 0; j < 4; ++j) {
            int row = wave * 32 + mf * 16 + lgrp * 4 + j;
            const float* mrow = mbase + (size_t)row * F_W;
            float mval[8];
#pragma unroll
            for (int nf = 0; nf < 8; ++nf) mval[nf] = mrow[nf * 16 + lrow];
            float mx = -1e30f;
#pragma unroll
            for (int nf = 0; nf < 8; ++nf) {
                sacc[mf][nf][j] += mval[nf];
                mx = fmaxf(mx, sacc[mf][nf][j]);
            }
#pragma unroll
            for (int d = 1; d < 16; d <<= 1) mx = fmaxf(mx, __shfl_xor(mx, d));
            float sum = 0.f;
#pragma unroll
            for (int nf = 0; nf < 8; ++nf) {
                float p = exp2f((sacc[mf][nf][j] - mx) * 1.44269504f);
                sacc[mf][nf][j] = p;
                sum += p;
            }
#pragma unroll
            for (int d = 1; d < 16; d <<= 1) sum += __shfl_xor(sum, d);
            float r = 1.0f / sum;
#pragma unroll
            for (int nf = 0; nf < 8; ++nf) sacc[mf][nf][j] *= r;
        }
    }
    __syncthreads();  // q/k reads done; overwrite with P
#pragma unroll
    for (int mf = 0; mf < 2; ++mf)
#pragma unroll
        for (int nf = 0; nf < 8; ++nf)
#pragma unroll
            for (int j = 0; j < 4; ++j) {
                int row = wave * 32 + mf * 16 + lgrp * 4 + j;
                int col = nf * 16 + lrow;
                p_lds[row * 128 + (col ^ ((row & 15) << 3))] = (bf16_t)sacc[mf][nf][j];
            }
    __syncthreads();

    // ---------------- Phase C: O = P @ V (M=128, N=64, K=128) --------------
    f32x4 oacc[2][4];
#pragma unroll
    for (int mf = 0; mf < 2; ++mf)
#pragma unroll
        for (int nf = 0; nf < 4; ++nf) oacc[mf][nf] = (f32x4)0.0f;

#pragma unroll
    for (int kb = 0; kb < 4; ++kb) {
        bf16x8 a[2], b[4];
#pragma unroll
        for (int mf = 0; mf < 2; ++mf) {
            int row = wave * 32 + mf * 16 + lrow;
            a[mf] = *(const bf16x8*)(p_lds + row * 128 + ((kb * 32 + lgrp * 8) ^ ((row & 15) << 3)));
        }
#pragma unroll
        for (int nf = 0; nf < 4; ++nf) {
            int d = nf * 16 + lrow;
            b[nf] = *(const bf16x8*)(vt_lds + d * 128 + ((kb * 32 + lgrp * 8) ^ ((d & 15) << 3)));
        }
#pragma unroll
        for (int mf = 0; mf < 2; ++mf)
#pragma unroll
            for (int nf = 0; nf < 4; ++nf)
                oacc[mf][nf] = MFMA16(a[mf], b[nf], oacc[mf][nf]);
    }

    bf16_t* obase = attn_out + (size_t)w * F_W * ED + h * HD;
#pragma unroll
    for (int mf = 0; mf < 2; ++mf)
#pragma unroll
        for (int nf = 0; nf < 4; ++nf)
#pragma unroll
            for (int j = 0; j < 4; ++j) {
                int row = wave * 32 + mf * 16 + lgrp * 4 + j;
                obase[(size_t)row * ED + nf * 16 + lrow] = (bf16_t)oacc[mf][nf][j];
            }
}

// ---------------- output projection GEMM: [65536,512]@[512,512]+b ----------
// XCD remap: blocks sharing an A-mtile land on the same XCD.
__global__ __launch_bounds__(256) void proj_kernel(
    const bf16_t* __restrict__ a_g,   // attn_out [65536][512] bf16
    const bf16_t* __restrict__ bt_g,  // proj_wt  [512][512] bf16 (n-major)
    const float* __restrict__ bias,   // [512]
    float* __restrict__ out) {        // [65536][512] fp32
    __shared__ __align__(16) bf16_t sm[8192];
    bf16_t* a_s = sm;         // [128][32]
    bf16_t* b_s = sm + 4096;  // [128][32]
    const int tid = threadIdx.x;
    const int wave = tid >> 6, lane = tid & 63;
    const int lrow = lane & 15, lgrp = lane >> 4;
    const int bid = blockIdx.x;                        // [0,2048)
    const int mtile = (bid & 7) * 64 + (bid >> 5);     // bijective remap
    const int ntile = (bid >> 3) & 3;
    const size_t m0 = (size_t)mtile * 128;
    const int n0 = ntile * 128;
    const int wrow_l = lane >> 2;
    const int wcol_l = ((((lane & 3) * 8)) ^ ((wrow_l & 3) << 3));

    f32x4 acc[2][8];
#pragma unroll
    for (int mf = 0; mf < 2; ++mf)
#pragma unroll
        for (int nf = 0; nf < 8; ++nf) acc[mf][nf] = (f32x4)0.0f;

    for (int kc = 0; kc < 16; ++kc) {
        const int k0 = kc * 32;
        __syncthreads();
#pragma unroll
        for (int i = 0; i < 2; ++i) {
            int c = wave * 2 + i;
            gload16(a_g + (m0 + c * 16 + wrow_l) * 512 + k0 + wcol_l, a_s + c * 512);
            gload16(bt_g + (size_t)(n0 + c * 16 + wrow_l) * 512 + k0 + wcol_l, b_s + c * 512);
        }
        __syncthreads();
        bf16x8 a[2], b[8];
#pragma unroll
        for (int mf = 0; mf < 2; ++mf) {
            int row = wave * 32 + mf * 16 + lrow;
            a[mf] = *(const bf16x8*)(a_s + row * 32 + ((lgrp * 8) ^ ((row & 3) << 3)));
        }
#pragma unroll
        for (int nf = 0; nf < 8; ++nf) {
            int row = nf * 16 + lrow;
            b[nf] = *(const bf16x8*)(b_s + row * 32 + ((lgrp * 8) ^ ((row & 3) << 3)));
        }
#pragma unroll
        for (int mf = 0; mf < 2; ++mf)
#pragma unroll
            for (int nf = 0; nf < 8; ++nf)
                acc[mf][nf] = MFMA16(a[mf], b[nf], acc[mf][nf]);
    }

#pragma unroll
    for (int nf = 0; nf < 8; ++nf) {
        int col = n0 + nf * 16 + lrow;
        float bv = bias[col];
#pragma unroll
        for (int mf = 0; mf < 2; ++mf)
#pragma unroll
            for (int j = 0; j < 4; ++j) {
                size_t row = m0 + wave * 32 + mf * 16 + lgrp * 4 + j;
                out[row * 512 + col] = acc[mf][nf][j] + bv;
            }
    }
}

extern "C" void kernel_launch(void* const* d_in, const int* in_sizes, int n_in,
                              void* d_out, int out_size, void* d_ws, size_t ws_size,
                              hipStream_t stream) {
    const float* x      = (const float*)d_in[0];
    const float* adj    = (const float*)d_in[1];
    const float* qkv_w  = (const float*)d_in[2];
    const float* qkv_b  = (const float*)d_in[3];
    const float* proj_w = (const float*)d_in[4];
    const float* proj_b = (const float*)d_in[5];
    float* out = (float*)d_out;

    bf16_t* attn_out = (bf16_t*)d_ws;
    bf16_t* qkv_wt   = attn_out + (size_t)B_NW * F_W * ED;
    bf16_t* proj_wt  = qkv_wt + 1536 * 512;

    prep_kernel<<<3072, 256, 0, stream>>>(qkv_w, proj_w, qkv_wt, proj_wt);
    fused_attn_kernel<<<B_NW * NH, 256, 0, stream>>>(x, adj, qkv_b, qkv_wt, attn_out);
    proj_kernel<<<(B_NW * F_W / 128) * (ED / 128), 256, 0, stream>>>(attn_out, proj_wt, proj_b, out);
}